// Round 5
// baseline (113.166 us; speedup 1.0000x reference)
//
#include <hip/hip_runtime.h>
#include <hip/hip_bf16.h>
#include <stdint.h>

// ---------------------------------------------------------------------------
// FMICL loss on MI355X — R14.
//   loss = -mean(s_pos) + 64 * ( sum_offdiag exp(-(2-2*G_ij)/2) / (N(N-1)) + 1e-8 )
//   G = Q @ Q^T, Q = fp4-e2m1(normalize(z1) * 32)  -- f8f6f4 MFMA, unit scales,
//   epilogue rescale g = acc / 1024. Gram symmetry makes any k-order / nibble
//   convention cancel between A and B.
//
// Attribution: R9=88.4 (4w staged), R12(+atomic finalize)=95.3 (fences cost
// ~7us -> out), R13 (8w staged)=86.6. Gram still ~25us vs ~5us pipe floors
// -> cost is the per-round issue->vmcnt(0)-drain->compute serialization,
// not bandwidth.
//
// R14 = ONE structural change: DELETE the LDS staging entirely. Q is 2 MB --
// L2-resident on every XCD -- so each lane loads its 16B MFMA fragment
// straight from global (identical bytes to the staged path; verified math
// untouched). Zero barriers / zero vmcnt drains in the K-loop; compiler
// pipelines global loads across MFMAs; 16 indep waves/CU hide L2 latency.
// (Precedent: learn_hip m168->m169, dropping L2-fit V-staging = +26%.)
//
// ws layout: [0, 2MB) fp4 Q ; float spos[4096] ; float star[528]
// ---------------------------------------------------------------------------

typedef unsigned short u16;
typedef uint8_t  u8;
typedef int    i32x4 __attribute__((ext_vector_type(4)));
typedef int    i32x8 __attribute__((ext_vector_type(8)));
typedef float  f32x4 __attribute__((ext_vector_type(4)));

constexpr int   D     = 1024;         // feature dim == GEMM K (elements)
constexpr int   DB    = D / 2;        // Q row stride in BYTES (fp4)
constexpr int   N     = 4096;         // rows per half
constexpr int   TM    = 128;          // tile M = tile N
constexpr int   NB    = N / TM;       // 32 tiles per side
constexpr int   NTRI  = NB * (NB + 1) / 2;  // 528 triangle tiles
constexpr float EPS   = 1e-8f;
constexpr float ALPHA = 64.0f;

// fp32 -> fp4 e2m1 nibble of round(|x|*32), sign bit 0x8.
__device__ __forceinline__ int fp4_of(float v) {
    const float y = fabsf(v) * 32.0f;
    int n = (y < 0.25f) ? 0 : (y < 0.75f) ? 1 : (y < 1.25f) ? 2 :
            (y < 1.75f) ? 3 : (y < 2.5f)  ? 4 : (y < 3.5f)  ? 5 :
            (y < 5.0f)  ? 6 : 7;
    return n | ((v < 0.0f) ? 8 : 0);
}

// ---------------------------------------------------------------------------
// Kernel 1: per row-pair i: normalize z1_i, z2_i (fp32), store fp4 Q row,
// compute s_pos_i -> spos[i]. Thread t packs elements [4t,4t+4) -> one u16.
// ---------------------------------------------------------------------------
__global__ __launch_bounds__(256) void norm_spos_kernel(
    const float* __restrict__ z, u8* __restrict__ q, float* __restrict__ spos)
{
    const int row = blockIdx.x;   // 0..4095
    const int t   = threadIdx.x;  // 0..255
    const int lane = t & 63, wave = t >> 6;

    const float4 a = ((const float4*)(z + (size_t)row       * D))[t];
    const float4 b = ((const float4*)(z + (size_t)(row + N) * D))[t];

    float s1 = a.x*a.x + a.y*a.y + a.z*a.z + a.w*a.w;
    float s2 = b.x*b.x + b.y*b.y + b.z*b.z + b.w*b.w;
    #pragma unroll
    for (int off = 32; off; off >>= 1) {
        s1 += __shfl_down(s1, off);
        s2 += __shfl_down(s2, off);
    }
    __shared__ float r1[4], r2[4], r3[4];
    if (lane == 0) { r1[wave] = s1; r2[wave] = s2; }
    __syncthreads();
    const float ss1 = r1[0] + r1[1] + r1[2] + r1[3];
    const float ss2 = r2[0] + r2[1] + r2[2] + r2[3];
    const float inv1 = 1.0f / fmaxf(sqrtf(ss1), 1e-12f);
    const float inv2 = 1.0f / fmaxf(sqrtf(ss2), 1e-12f);

    float4 an, bn;
    an.x = a.x * inv1; an.y = a.y * inv1; an.z = a.z * inv1; an.w = a.w * inv1;
    bn.x = b.x * inv2; bn.y = b.y * inv2; bn.z = b.z * inv2; bn.w = b.w * inv2;

    const int pk = fp4_of(an.x) | (fp4_of(an.y) << 4) |
                   (fp4_of(an.z) << 8) | (fp4_of(an.w) << 12);
    ((u16*)q)[row * (DB / 2) + t] = (u16)pk;

    const float dx = an.x - bn.x, dy = an.y - bn.y;
    const float dz = an.z - bn.z, dw = an.w - bn.w;
    float dp = dx*dx + dy*dy + dz*dz + dw*dw;
    #pragma unroll
    for (int off = 32; off; off >>= 1) dp += __shfl_down(dp, off);
    if (lane == 0) r3[wave] = dp;
    __syncthreads();
    if (t == 0) {
        const float d_pos = r3[0] + r3[1] + r3[2] + r3[3];
        const float g     = expf(-0.5f * d_pos);
        spos[row] = logf(g + EPS) + 1.0f;
    }
}

// ---------------------------------------------------------------------------
// Kernel 2: fused Gram + exp-sum over the (bi<=bj) triangle of 128x128 tiles.
// 512 threads = 8 waves in 2x4; each wave a 64x32 sub-tile = 4x2 of
// 16x16x128 fp4 MFMA (f8f6f4, cbsz=blgp=4, unit scales).
//
// NO LDS, NO barriers in the K-loop: lane (fr,fq) loads its 16B fragment
// (granule kk*4+fq of row base+fr) directly from the L2-resident Q. The
// bytes delivered per lane are identical to the staged path (verified).
// 8 kk-steps of K=128 each cover the full D=1024.
// ---------------------------------------------------------------------------
__global__ __launch_bounds__(512, 4) void gram_kernel(
    const u8* __restrict__ Q, float* __restrict__ star_part)
{
    __shared__ float wsum[8];

    // triangle decode: blockIdx.x -> (bi, bj), bi <= bj
    int bi = 0, rem = blockIdx.x;
    while (rem >= NB - bi) { rem -= NB - bi; ++bi; }
    const int bj    = bi + rem;
    const int rowA0 = bi * TM, rowB0 = bj * TM;
    const bool diag = (bi == bj);

    const int t    = threadIdx.x;   // 0..511
    const int lane = t & 63;
    const int wave = t >> 6;        // 0..7
    const int wm   = (wave & 1) * 64;    // m-half
    const int wn   = (wave >> 1) * 32;   // n-quarter
    const int fr   = lane & 15;          // fragment row (m or n)
    const int fq   = lane >> 4;          // k-quad 0..3 (32 elements each)

    // per-lane fragment base pointers: row (base+fr), byte fq*16; kk walks
    // +64 B per step (fits the 13-bit signed global offset immediate).
    const u8* pA[4]; const u8* pB[2];
    #pragma unroll
    for (int mt = 0; mt < 4; ++mt)
        pA[mt] = Q + (size_t)(rowA0 + wm + mt * 16 + fr) * DB + fq * 16;
    #pragma unroll
    for (int nt = 0; nt < 2; ++nt)
        pB[nt] = Q + (size_t)(rowB0 + wn + nt * 16 + fr) * DB + fq * 16;

    f32x4 acc[4][2];
    #pragma unroll
    for (int mt = 0; mt < 4; ++mt)
        #pragma unroll
        for (int nt = 0; nt < 2; ++nt)
            acc[mt][nt] = f32x4{0.f, 0.f, 0.f, 0.f};

    #pragma unroll
    for (int kk = 0; kk < 8; ++kk) {       // 8 x K=128 covers D=1024
        const int o = kk * 64;             // byte step per K=128 (4 granules)
        i32x8 bf[2];
        #pragma unroll
        for (int nt = 0; nt < 2; ++nt) {
            const i32x4 v = *(const i32x4*)(pB[nt] + o);
            bf[nt][0] = v[0]; bf[nt][1] = v[1]; bf[nt][2] = v[2]; bf[nt][3] = v[3];
            bf[nt][4] = 0;    bf[nt][5] = 0;    bf[nt][6] = 0;    bf[nt][7] = 0;
        }
        #pragma unroll
        for (int mt = 0; mt < 4; ++mt) {
            const i32x4 v = *(const i32x4*)(pA[mt] + o);
            i32x8 af;
            af[0] = v[0]; af[1] = v[1]; af[2] = v[2]; af[3] = v[3];
            af[4] = 0;    af[5] = 0;    af[6] = 0;    af[7] = 0;
            #pragma unroll
            for (int nt = 0; nt < 2; ++nt)
                acc[mt][nt] = __builtin_amdgcn_mfma_scale_f32_16x16x128_f8f6f4(
                    af, bf[nt], acc[mt][nt],
                    4, 4,               // cbsz=fp4, blgp=fp4
                    0, 0x7f7f7f7f,      // scale A: e8m0 127 = 1.0
                    0, 0x7f7f7f7f);     // scale B
        }
    }

    // Epilogue: g = acc/1024 (undo 32x per-operand encoding);
    // e = exp(-max(2-2g,0)/2); diag tile masks i==j; off-diag x2.
    constexpr float INV = 1.0f / 1024.0f;
    float lsum = 0.0f;
    #pragma unroll
    for (int mt = 0; mt < 4; ++mt) {
        #pragma unroll
        for (int nt = 0; nt < 2; ++nt) {
            #pragma unroll
            for (int r = 0; r < 4; ++r) {
                const float g  = acc[mt][nt][r] * INV;
                const int   gi = wm + mt * 16 + fq * 4 + r;   // local row
                const int   gj = wn + nt * 16 + fr;           // local col
                const float d2 = fmaxf(2.0f - 2.0f * g, 0.0f);
                const float e  = __expf(-0.5f * d2);
                lsum += (diag && gi == gj) ? 0.0f : e;
            }
        }
    }
    #pragma unroll
    for (int off = 32; off; off >>= 1) lsum += __shfl_down(lsum, off);
    if (lane == 0) wsum[wave] = lsum;
    __syncthreads();
    if (t == 0) {
        float s = 0.0f;
        #pragma unroll
        for (int w = 0; w < 8; ++w) s += wsum[w];
        star_part[blockIdx.x] = (diag ? 1.0f : 2.0f) * s;
    }
}

// ---------------------------------------------------------------------------
// Kernel 3: sum the partials, assemble the scalar loss.
// ---------------------------------------------------------------------------
__global__ __launch_bounds__(256) void finalize_kernel(
    const float* __restrict__ spos, const float* __restrict__ star,
    float* __restrict__ out)
{
    const int t = threadIdx.x, lane = t & 63, wave = t >> 6;
    float s1 = 0.0f, s2 = 0.0f;
    for (int i = t; i < N;    i += 256) s1 += spos[i];
    for (int i = t; i < NTRI; i += 256) s2 += star[i];
    #pragma unroll
    for (int off = 32; off; off >>= 1) {
        s1 += __shfl_down(s1, off);
        s2 += __shfl_down(s2, off);
    }
    __shared__ float r1[4], r2[4];
    if (lane == 0) { r1[wave] = s1; r2[wave] = s2; }
    __syncthreads();
    if (t == 0) {
        const float spos_sum = r1[0] + r1[1] + r1[2] + r1[3];
        const float star_sum = r2[0] + r2[1] + r2[2] + r2[3];
        const float star_mean = star_sum / ((float)N * (float)(N - 1)) + EPS;
        out[0] = -spos_sum / (float)N + ALPHA * star_mean;
    }
}

// ---------------------------------------------------------------------------
extern "C" void kernel_launch(void* const* d_in, const int* in_sizes, int n_in,
                              void* d_out, int out_size, void* d_ws, size_t ws_size,
                              hipStream_t stream)
{
    (void)in_sizes; (void)n_in; (void)out_size; (void)ws_size;
    const float* z    = (const float*)d_in[0];
    float*       out  = (float*)d_out;
    u8*          q    = (u8*)d_ws;                                   // 2 MB fp4
    float*       spos = (float*)((char*)d_ws + (size_t)N * DB);      // 4096 f
    float*       star = spos + N;                                    // 528 f

    hipLaunchKernelGGL(norm_spos_kernel, dim3(N),    dim3(256), 0, stream, z, q, spos);
    hipLaunchKernelGGL(gram_kernel,      dim3(NTRI), dim3(512), 0, stream, q, star);
    hipLaunchKernelGGL(finalize_kernel,  dim3(1),    dim3(256), 0, stream, spos, star, out);
}

// Round 6
// 90.731 us; speedup vs baseline: 1.2473x; 1.2473x over previous
//
#include <hip/hip_runtime.h>
#include <hip/hip_bf16.h>
#include <stdint.h>

// ---------------------------------------------------------------------------
// FMICL loss on MI355X — R15.
//   loss = -mean(s_pos) + 64 * ( sum_offdiag exp(-(2-2*G_ij)/2) / (N(N-1)) + 1e-8 )
//   G = Q @ Q^T, Q = fp4-e2m1(normalize(z1) * 32)  -- f8f6f4 MFMA, unit scales,
//   epilogue rescale g = acc / 1024. Gram symmetry makes any k-order / nibble
//   convention cancel between A and B.
//
// Attribution: R9=88.4 (4w staged), R12(atomic finalize)=95.3 (out),
// R13 (8w staged)=86.6 BEST, R14 (no-LDS direct-global)=113.2 (out: tripled
// L2 traffic + exposed load->MFMA latency).
//
// R15 = R13 + ONE change (T4, counted vmcnt): gram double-buffers the LDS
// staging with s_waitcnt vmcnt(4) + raw s_barrier per round instead of
// __syncthreads' vmcnt(0) drain. R11's "double buffer" used __syncthreads,
// which DRAINS the just-issued prefetch (guide: drain0 pipeline == no
// pipeline; the gain IS the counted wait). Prefetch loads now stay in
// flight across the barrier; each round's L2 round-trip hides under the
// previous round's 32 MFMAs. LDS 64KB/block, 2 blocks/CU = 128 <= 160KB.
//
// ws layout: [0, 2MB) fp4 Q ; float spos[4096] ; float star[528]
// ---------------------------------------------------------------------------

#define AS1 __attribute__((address_space(1)))
#define AS3 __attribute__((address_space(3)))

typedef unsigned short u16;
typedef uint8_t  u8;
typedef int    i32x4 __attribute__((ext_vector_type(4)));
typedef int    i32x8 __attribute__((ext_vector_type(8)));
typedef float  f32x4 __attribute__((ext_vector_type(4)));

constexpr int   D     = 1024;         // feature dim == GEMM K (elements)
constexpr int   DB    = D / 2;        // Q row stride in BYTES (fp4)
constexpr int   N     = 4096;         // rows per half
constexpr int   TM    = 128;          // tile M = tile N
constexpr int   BKB   = 128;          // K-step per staging round in BYTES (=256 elems)
constexpr int   NB    = N / TM;       // 32 tiles per side
constexpr int   NTRI  = NB * (NB + 1) / 2;  // 528 triangle tiles
constexpr float EPS   = 1e-8f;
constexpr float ALPHA = 64.0f;

__device__ __forceinline__ void async_load16(const void* g, void* l) {
    __builtin_amdgcn_global_load_lds((AS1 void*)g, (AS3 void*)l, 16, 0, 0);
}

// fp32 -> fp4 e2m1 nibble of round(|x|*32), sign bit 0x8.
__device__ __forceinline__ int fp4_of(float v) {
    const float y = fabsf(v) * 32.0f;
    int n = (y < 0.25f) ? 0 : (y < 0.75f) ? 1 : (y < 1.25f) ? 2 :
            (y < 1.75f) ? 3 : (y < 2.5f)  ? 4 : (y < 3.5f)  ? 5 :
            (y < 5.0f)  ? 6 : 7;
    return n | ((v < 0.0f) ? 8 : 0);
}

// ---------------------------------------------------------------------------
// Kernel 1: per row-pair i: normalize z1_i, z2_i (fp32), store fp4 Q row,
// compute s_pos_i -> spos[i]. Thread t packs elements [4t,4t+4) -> one u16.
// ---------------------------------------------------------------------------
__global__ __launch_bounds__(256) void norm_spos_kernel(
    const float* __restrict__ z, u8* __restrict__ q, float* __restrict__ spos)
{
    const int row = blockIdx.x;   // 0..4095
    const int t   = threadIdx.x;  // 0..255
    const int lane = t & 63, wave = t >> 6;

    const float4 a = ((const float4*)(z + (size_t)row       * D))[t];
    const float4 b = ((const float4*)(z + (size_t)(row + N) * D))[t];

    float s1 = a.x*a.x + a.y*a.y + a.z*a.z + a.w*a.w;
    float s2 = b.x*b.x + b.y*b.y + b.z*b.z + b.w*b.w;
    #pragma unroll
    for (int off = 32; off; off >>= 1) {
        s1 += __shfl_down(s1, off);
        s2 += __shfl_down(s2, off);
    }
    __shared__ float r1[4], r2[4], r3[4];
    if (lane == 0) { r1[wave] = s1; r2[wave] = s2; }
    __syncthreads();
    const float ss1 = r1[0] + r1[1] + r1[2] + r1[3];
    const float ss2 = r2[0] + r2[1] + r2[2] + r2[3];
    const float inv1 = 1.0f / fmaxf(sqrtf(ss1), 1e-12f);
    const float inv2 = 1.0f / fmaxf(sqrtf(ss2), 1e-12f);

    float4 an, bn;
    an.x = a.x * inv1; an.y = a.y * inv1; an.z = a.z * inv1; an.w = a.w * inv1;
    bn.x = b.x * inv2; bn.y = b.y * inv2; bn.z = b.z * inv2; bn.w = b.w * inv2;

    const int pk = fp4_of(an.x) | (fp4_of(an.y) << 4) |
                   (fp4_of(an.z) << 8) | (fp4_of(an.w) << 12);
    ((u16*)q)[row * (DB / 2) + t] = (u16)pk;

    const float dx = an.x - bn.x, dy = an.y - bn.y;
    const float dz = an.z - bn.z, dw = an.w - bn.w;
    float dp = dx*dx + dy*dy + dz*dz + dw*dw;
    #pragma unroll
    for (int off = 32; off; off >>= 1) dp += __shfl_down(dp, off);
    if (lane == 0) r3[wave] = dp;
    __syncthreads();
    if (t == 0) {
        const float d_pos = r3[0] + r3[1] + r3[2] + r3[3];
        const float g     = expf(-0.5f * d_pos);
        spos[row] = logf(g + EPS) + 1.0f;
    }
}

// ---------------------------------------------------------------------------
// Kernel 2: fused Gram + exp-sum over the (bi<=bj) triangle of 128x128 tiles.
// 512 threads = 8 waves in 2x4; each wave a 64x32 sub-tile = 4x2 of
// 16x16x128 fp4 MFMA (f8f6f4, cbsz=blgp=4, unit scales). 4 K-rounds of 256
// elements (128 B), double-buffered with COUNTED vmcnt (T4):
//   stage(r+1) -> s_waitcnt vmcnt(4) [r's 4 loads done, prefetch in flight]
//   -> s_barrier -> compute(r) -> s_barrier [buf reuse protection].
// Each wave passes its own vmcnt wait before the barrier, so after the
// barrier ALL waves' round-r DMA is in LDS (vmcnt is per-wave).
//
// LDS tiles [128 rows][128 B]: 16B granule g of row r stored at slot g^(r&7).
// global_load_lds dest stays linear in lane order; only the global SOURCE
// granule is permuted. Fragment = ONE b128 per lane (16 B = 32 fp4 = K-slice).
// ---------------------------------------------------------------------------
__global__ __launch_bounds__(512, 4) void gram_kernel(
    const u8* __restrict__ Q, float* __restrict__ star_part)
{
    __shared__ __align__(16) u8 lA[2][TM * BKB];  // 2 x 16 KB
    __shared__ __align__(16) u8 lB[2][TM * BKB];  // 2 x 16 KB
    __shared__ float wsum[8];

    // triangle decode: blockIdx.x -> (bi, bj), bi <= bj
    int bi = 0, rem = blockIdx.x;
    while (rem >= NB - bi) { rem -= NB - bi; ++bi; }
    const int bj    = bi + rem;
    const int rowA0 = bi * TM, rowB0 = bj * TM;
    const bool diag = (bi == bj);

    const int t    = threadIdx.x;   // 0..511
    const int lane = t & 63;
    const int wave = t >> 6;        // 0..7
    const int wm   = (wave & 1) * 64;    // m-half
    const int wn   = (wave >> 1) * 32;   // n-quarter
    const int fr   = lane & 15;          // fragment row (m or n)
    const int fq   = lane >> 4;          // k-quad 0..3 (32 elements each)

    // staging: 1024 16B-granules per tile, thread handles p = t + 512*j
    const u8* gA[2]; const u8* gB[2]; int dOff[2];
    #pragma unroll
    for (int j = 0; j < 2; ++j) {
        const int p = t + 512 * j;
        const int r = p >> 3;
        const int c = (p & 7) ^ (r & 7);   // XOR swizzle (self-inverse)
        gA[j] = Q + (size_t)(rowA0 + r) * DB + c * 16;
        gB[j] = Q + (size_t)(rowB0 + r) * DB + c * 16;
        dOff[j] = p * 16;
    }

    f32x4 acc[4][2];
    #pragma unroll
    for (int mt = 0; mt < 4; ++mt)
        #pragma unroll
        for (int nt = 0; nt < 2; ++nt)
            acc[mt][nt] = f32x4{0.f, 0.f, 0.f, 0.f};

    auto stage = [&](int k0, int buf) {
        #pragma unroll
        for (int j = 0; j < 2; ++j) {
            async_load16(gA[j] + k0, &lA[buf][dOff[j]]);
            async_load16(gB[j] + k0, &lB[buf][dOff[j]]);
        }
    };

    auto compute = [&](int buf) {
        #pragma unroll
        for (int kk = 0; kk < 2; ++kk) {     // two K=128 MFMA steps per round
            i32x8 bf[2];
            #pragma unroll
            for (int nt = 0; nt < 2; ++nt) {
                const int r = wn + nt * 16 + fr;
                const i32x4 v = ((const i32x4*)&lB[buf][r * BKB])[(kk * 4 + fq) ^ (r & 7)];
                bf[nt][0] = v[0]; bf[nt][1] = v[1]; bf[nt][2] = v[2]; bf[nt][3] = v[3];
                bf[nt][4] = 0;    bf[nt][5] = 0;    bf[nt][6] = 0;    bf[nt][7] = 0;
            }
            #pragma unroll
            for (int mt = 0; mt < 4; ++mt) {
                const int r = wm + mt * 16 + fr;
                const i32x4 v = ((const i32x4*)&lA[buf][r * BKB])[(kk * 4 + fq) ^ (r & 7)];
                i32x8 af;
                af[0] = v[0]; af[1] = v[1]; af[2] = v[2]; af[3] = v[3];
                af[4] = 0;    af[5] = 0;    af[6] = 0;    af[7] = 0;
                #pragma unroll
                for (int nt = 0; nt < 2; ++nt)
                    acc[mt][nt] = __builtin_amdgcn_mfma_scale_f32_16x16x128_f8f6f4(
                        af, bf[nt], acc[mt][nt],
                        4, 4,               // cbsz=fp4, blgp=fp4
                        0, 0x7f7f7f7f,      // scale A: e8m0 127 = 1.0
                        0, 0x7f7f7f7f);     // scale B
            }
        }
    };

    // T4 pipeline: prefetch next round, counted wait on current, barrier,
    // compute, barrier. vmcnt never drains to 0 until the last round.
    stage(0, 0);
    #pragma unroll
    for (int rd = 0; rd < 4; ++rd) {
        const int cur = rd & 1;
        if (rd < 3) {
            stage((rd + 1) * BKB, cur ^ 1);
            asm volatile("s_waitcnt vmcnt(4)" ::: "memory");  // cur's 4 loads done
        } else {
            asm volatile("s_waitcnt vmcnt(0)" ::: "memory");  // final drain
        }
        __builtin_amdgcn_s_barrier();    // all waves passed their vmcnt wait
        compute(cur);
        __builtin_amdgcn_s_barrier();    // protect cur before round rd+2 rewrites
    }

    // Epilogue: g = acc/1024 (undo 32x per-operand encoding);
    // e = exp(-max(2-2g,0)/2); diag tile masks i==j; off-diag x2.
    constexpr float INV = 1.0f / 1024.0f;
    float lsum = 0.0f;
    #pragma unroll
    for (int mt = 0; mt < 4; ++mt) {
        #pragma unroll
        for (int nt = 0; nt < 2; ++nt) {
            #pragma unroll
            for (int r = 0; r < 4; ++r) {
                const float g  = acc[mt][nt][r] * INV;
                const int   gi = wm + mt * 16 + fq * 4 + r;   // local row
                const int   gj = wn + nt * 16 + fr;           // local col
                const float d2 = fmaxf(2.0f - 2.0f * g, 0.0f);
                const float e  = __expf(-0.5f * d2);
                lsum += (diag && gi == gj) ? 0.0f : e;
            }
        }
    }
    #pragma unroll
    for (int off = 32; off; off >>= 1) lsum += __shfl_down(lsum, off);
    if (lane == 0) wsum[wave] = lsum;
    __syncthreads();
    if (t == 0) {
        float s = 0.0f;
        #pragma unroll
        for (int w = 0; w < 8; ++w) s += wsum[w];
        star_part[blockIdx.x] = (diag ? 1.0f : 2.0f) * s;
    }
}

// ---------------------------------------------------------------------------
// Kernel 3: sum the partials, assemble the scalar loss.
// ---------------------------------------------------------------------------
__global__ __launch_bounds__(256) void finalize_kernel(
    const float* __restrict__ spos, const float* __restrict__ star,
    float* __restrict__ out)
{
    const int t = threadIdx.x, lane = t & 63, wave = t >> 6;
    float s1 = 0.0f, s2 = 0.0f;
    for (int i = t; i < N;    i += 256) s1 += spos[i];
    for (int i = t; i < NTRI; i += 256) s2 += star[i];
    #pragma unroll
    for (int off = 32; off; off >>= 1) {
        s1 += __shfl_down(s1, off);
        s2 += __shfl_down(s2, off);
    }
    __shared__ float r1[4], r2[4];
    if (lane == 0) { r1[wave] = s1; r2[wave] = s2; }
    __syncthreads();
    if (t == 0) {
        const float spos_sum = r1[0] + r1[1] + r1[2] + r1[3];
        const float star_sum = r2[0] + r2[1] + r2[2] + r2[3];
        const float star_mean = star_sum / ((float)N * (float)(N - 1)) + EPS;
        out[0] = -spos_sum / (float)N + ALPHA * star_mean;
    }
}

// ---------------------------------------------------------------------------
extern "C" void kernel_launch(void* const* d_in, const int* in_sizes, int n_in,
                              void* d_out, int out_size, void* d_ws, size_t ws_size,
                              hipStream_t stream)
{
    (void)in_sizes; (void)n_in; (void)out_size; (void)ws_size;
    const float* z    = (const float*)d_in[0];
    float*       out  = (float*)d_out;
    u8*          q    = (u8*)d_ws;                                   // 2 MB fp4
    float*       spos = (float*)((char*)d_ws + (size_t)N * DB);      // 4096 f
    float*       star = spos + N;                                    // 528 f

    hipLaunchKernelGGL(norm_spos_kernel, dim3(N),    dim3(256), 0, stream, z, q, spos);
    hipLaunchKernelGGL(gram_kernel,      dim3(NTRI), dim3(512), 0, stream, q, star);
    hipLaunchKernelGGL(finalize_kernel,  dim3(1),    dim3(256), 0, stream, spos, star, out);
}

// Round 8
// 87.466 us; speedup vs baseline: 1.2938x; 1.0373x over previous
//
#include <hip/hip_runtime.h>
#include <hip/hip_bf16.h>
#include <stdint.h>

// ---------------------------------------------------------------------------
// FMICL loss on MI355X — R17.
//   loss = -mean(s_pos) + 64 * ( sum_offdiag exp(-(2-2*G_ij)/2) / (N(N-1)) + 1e-8 )
//   G = Q @ Q^T, Q = fp4-e2m1(normalize(z1) * 32)  -- f8f6f4 MFMA, unit scales,
//   epilogue rescale g = acc / 1024. Gram symmetry makes any k-order / nibble
//   convention cancel between A and B.
//
// Attribution: R9=88.4 (4w, 3 blk/CU, single round), R12(+fence finalize)=95.3
// out, R13 (8w, 2 blk/CU)=86.6 BEST, R14 (no-LDS)=113.2 out, R15 (counted
// vmcnt dbuf)=90.7 out, R16 (atomic finalize)=container crash -> fusion line
// abandoned.
//
// R17 = R13 + ONE change: 3 blocks/CU co-residency (single-round scheduling
// of the 528 tiles instead of 512+16 two-round) via a VGPR diet:
//  - staging addresses carried as 32-bit per-lane offsets off a uniform
//    (SGPR) Q base instead of 4x 64-bit pointers (16 -> 4 VGPRs); hipcc
//    emits global_load_lds saddr+voffset.
//  - __launch_bounds__(512, 6): 6 waves/EU -> VGPR cap 85 -> 24 waves/CU
//    = 3 blocks. LDS 3 x 32 KB = 96 <= 160 KB.
// Gram math / LDS swizzle / round structure are R13-verbatim.
//
// ws layout: [0, 2MB) fp4 Q ; float spos[4096] ; float star[528]
// ---------------------------------------------------------------------------

#define AS1 __attribute__((address_space(1)))
#define AS3 __attribute__((address_space(3)))

typedef unsigned short u16;
typedef uint8_t  u8;
typedef int    i32x4 __attribute__((ext_vector_type(4)));
typedef int    i32x8 __attribute__((ext_vector_type(8)));
typedef float  f32x4 __attribute__((ext_vector_type(4)));

constexpr int   D     = 1024;         // feature dim == GEMM K (elements)
constexpr int   DB    = D / 2;        // Q row stride in BYTES (fp4)
constexpr int   N     = 4096;         // rows per half
constexpr int   TM    = 128;          // tile M = tile N
constexpr int   BKB   = 128;          // K-step per staging round in BYTES (=256 elems)
constexpr int   NB    = N / TM;       // 32 tiles per side
constexpr int   NTRI  = NB * (NB + 1) / 2;  // 528 triangle tiles
constexpr float EPS   = 1e-8f;
constexpr float ALPHA = 64.0f;

__device__ __forceinline__ void async_load16(const void* g, void* l) {
    __builtin_amdgcn_global_load_lds((AS1 void*)g, (AS3 void*)l, 16, 0, 0);
}

// fp32 -> fp4 e2m1 nibble of round(|x|*32), sign bit 0x8.
__device__ __forceinline__ int fp4_of(float v) {
    const float y = fabsf(v) * 32.0f;
    int n = (y < 0.25f) ? 0 : (y < 0.75f) ? 1 : (y < 1.25f) ? 2 :
            (y < 1.75f) ? 3 : (y < 2.5f)  ? 4 : (y < 3.5f)  ? 5 :
            (y < 5.0f)  ? 6 : 7;
    return n | ((v < 0.0f) ? 8 : 0);
}

// ---------------------------------------------------------------------------
// Kernel 1: per row-pair i: normalize z1_i, z2_i (fp32), store fp4 Q row,
// compute s_pos_i -> spos[i]. Thread t packs elements [4t,4t+4) -> one u16.
// ---------------------------------------------------------------------------
__global__ __launch_bounds__(256) void norm_spos_kernel(
    const float* __restrict__ z, u8* __restrict__ q, float* __restrict__ spos)
{
    const int row = blockIdx.x;   // 0..4095
    const int t   = threadIdx.x;  // 0..255
    const int lane = t & 63, wave = t >> 6;

    const float4 a = ((const float4*)(z + (size_t)row       * D))[t];
    const float4 b = ((const float4*)(z + (size_t)(row + N) * D))[t];

    float s1 = a.x*a.x + a.y*a.y + a.z*a.z + a.w*a.w;
    float s2 = b.x*b.x + b.y*b.y + b.z*b.z + b.w*b.w;
    #pragma unroll
    for (int off = 32; off; off >>= 1) {
        s1 += __shfl_down(s1, off);
        s2 += __shfl_down(s2, off);
    }
    __shared__ float r1[4], r2[4], r3[4];
    if (lane == 0) { r1[wave] = s1; r2[wave] = s2; }
    __syncthreads();
    const float ss1 = r1[0] + r1[1] + r1[2] + r1[3];
    const float ss2 = r2[0] + r2[1] + r2[2] + r2[3];
    const float inv1 = 1.0f / fmaxf(sqrtf(ss1), 1e-12f);
    const float inv2 = 1.0f / fmaxf(sqrtf(ss2), 1e-12f);

    float4 an, bn;
    an.x = a.x * inv1; an.y = a.y * inv1; an.z = a.z * inv1; an.w = a.w * inv1;
    bn.x = b.x * inv2; bn.y = b.y * inv2; bn.z = b.z * inv2; bn.w = b.w * inv2;

    const int pk = fp4_of(an.x) | (fp4_of(an.y) << 4) |
                   (fp4_of(an.z) << 8) | (fp4_of(an.w) << 12);
    ((u16*)q)[row * (DB / 2) + t] = (u16)pk;

    const float dx = an.x - bn.x, dy = an.y - bn.y;
    const float dz = an.z - bn.z, dw = an.w - bn.w;
    float dp = dx*dx + dy*dy + dz*dz + dw*dw;
    #pragma unroll
    for (int off = 32; off; off >>= 1) dp += __shfl_down(dp, off);
    if (lane == 0) r3[wave] = dp;
    __syncthreads();
    if (t == 0) {
        const float d_pos = r3[0] + r3[1] + r3[2] + r3[3];
        const float g     = expf(-0.5f * d_pos);
        spos[row] = logf(g + EPS) + 1.0f;
    }
}

// ---------------------------------------------------------------------------
// Kernel 2: fused Gram + exp-sum over the (bi<=bj) triangle of 128x128 tiles.
// 512 threads = 8 waves in 2x4; each wave a 64x32 sub-tile = 4x2 of
// 16x16x128 fp4 MFMA (f8f6f4, cbsz=blgp=4, unit scales). 4 K-iters of 256
// elements (128 B). launch_bounds(512,6): VGPR<=85 -> 3 blocks/CU ->
// all 528 tiles co-resident in ONE scheduling round (768 slots).
//
// LDS tiles [128 rows][128 B]: 16B granule g of row r stored at slot g^(r&7).
// global_load_lds dest stays linear in lane order; only the global SOURCE
// granule is permuted. Fragment = ONE b128 per lane (16 B = 32 fp4 = K-slice).
// Staging addresses: uniform Q base (SGPR) + 32-bit per-lane offsets.
// ---------------------------------------------------------------------------
__global__ __launch_bounds__(512, 6) void gram_kernel(
    const u8* __restrict__ Q, float* __restrict__ star_part)
{
    __shared__ __align__(16) u8 lA[TM * BKB];  // 16 KB
    __shared__ __align__(16) u8 lB[TM * BKB];  // 16 KB
    __shared__ float wsum[8];

    // triangle decode: blockIdx.x -> (bi, bj), bi <= bj
    int bi = 0, rem = blockIdx.x;
    while (rem >= NB - bi) { rem -= NB - bi; ++bi; }
    const int bj    = bi + rem;
    const int rowA0 = bi * TM, rowB0 = bj * TM;
    const bool diag = (bi == bj);

    const int t    = threadIdx.x;   // 0..511
    const int lane = t & 63;
    const int wave = t >> 6;        // 0..7
    const int wm   = (wave & 1) * 64;    // m-half
    const int wn   = (wave >> 1) * 32;   // n-quarter
    const int fr   = lane & 15;          // fragment row (m or n)
    const int fq   = lane >> 4;          // k-quad 0..3 (32 elements each)

    // staging: 1024 16B-granules per tile, thread handles p = t + 512*j.
    // 32-bit offsets off the uniform Q base (saves 12 VGPRs vs 64b pointers).
    int offA[2], offB[2], dOff[2];
    #pragma unroll
    for (int j = 0; j < 2; ++j) {
        const int p = t + 512 * j;
        const int r = p >> 3;
        const int c = (p & 7) ^ (r & 7);   // XOR swizzle (self-inverse)
        offA[j] = (rowA0 + r) * DB + c * 16;
        offB[j] = (rowB0 + r) * DB + c * 16;
        dOff[j] = p * 16;
    }

    f32x4 acc[4][2];
    #pragma unroll
    for (int mt = 0; mt < 4; ++mt)
        #pragma unroll
        for (int nt = 0; nt < 2; ++nt)
            acc[mt][nt] = f32x4{0.f, 0.f, 0.f, 0.f};

    for (int k0 = 0; k0 < DB; k0 += BKB) {   // byte offset within Q row
        #pragma unroll
        for (int j = 0; j < 2; ++j) {
            async_load16(Q + offA[j] + k0, &lA[dOff[j]]);
            async_load16(Q + offB[j] + k0, &lB[dOff[j]]);
        }
        __syncthreads();   // drains vmcnt for the LDS-DMA

        #pragma unroll
        for (int kk = 0; kk < 2; ++kk) {     // two K=128 MFMA steps per stage
            i32x8 bf[2];
            #pragma unroll
            for (int nt = 0; nt < 2; ++nt) {
                const int r = wn + nt * 16 + fr;
                const i32x4 v = ((const i32x4*)&lB[r * BKB])[(kk * 4 + fq) ^ (r & 7)];
                bf[nt][0] = v[0]; bf[nt][1] = v[1]; bf[nt][2] = v[2]; bf[nt][3] = v[3];
                bf[nt][4] = 0;    bf[nt][5] = 0;    bf[nt][6] = 0;    bf[nt][7] = 0;
            }
            #pragma unroll
            for (int mt = 0; mt < 4; ++mt) {
                const int r = wm + mt * 16 + fr;
                const i32x4 v = ((const i32x4*)&lA[r * BKB])[(kk * 4 + fq) ^ (r & 7)];
                i32x8 af;
                af[0] = v[0]; af[1] = v[1]; af[2] = v[2]; af[3] = v[3];
                af[4] = 0;    af[5] = 0;    af[6] = 0;    af[7] = 0;
                #pragma unroll
                for (int nt = 0; nt < 2; ++nt)
                    acc[mt][nt] = __builtin_amdgcn_mfma_scale_f32_16x16x128_f8f6f4(
                        af, bf[nt], acc[mt][nt],
                        4, 4,               // cbsz=fp4, blgp=fp4
                        0, 0x7f7f7f7f,      // scale A: e8m0 127 = 1.0
                        0, 0x7f7f7f7f);     // scale B
            }
        }

        __syncthreads();   // protect LDS before next staging round
    }

    // Epilogue: g = acc/1024 (undo 32x per-operand encoding);
    // e = exp(-max(2-2g,0)/2); diag tile masks i==j; off-diag x2.
    constexpr float INV = 1.0f / 1024.0f;
    float lsum = 0.0f;
    #pragma unroll
    for (int mt = 0; mt < 4; ++mt) {
        #pragma unroll
        for (int nt = 0; nt < 2; ++nt) {
            #pragma unroll
            for (int r = 0; r < 4; ++r) {
                const float g  = acc[mt][nt][r] * INV;
                const int   gi = wm + mt * 16 + fq * 4 + r;   // local row
                const int   gj = wn + nt * 16 + fr;           // local col
                const float d2 = fmaxf(2.0f - 2.0f * g, 0.0f);
                const float e  = __expf(-0.5f * d2);
                lsum += (diag && gi == gj) ? 0.0f : e;
            }
        }
    }
    #pragma unroll
    for (int off = 32; off; off >>= 1) lsum += __shfl_down(lsum, off);
    if (lane == 0) wsum[wave] = lsum;
    __syncthreads();
    if (t == 0) {
        float s = 0.0f;
        #pragma unroll
        for (int w = 0; w < 8; ++w) s += wsum[w];
        star_part[blockIdx.x] = (diag ? 1.0f : 2.0f) * s;
    }
}

// ---------------------------------------------------------------------------
// Kernel 3: sum the partials, assemble the scalar loss.
// ---------------------------------------------------------------------------
__global__ __launch_bounds__(256) void finalize_kernel(
    const float* __restrict__ spos, const float* __restrict__ star,
    float* __restrict__ out)
{
    const int t = threadIdx.x, lane = t & 63, wave = t >> 6;
    float s1 = 0.0f, s2 = 0.0f;
    for (int i = t; i < N;    i += 256) s1 += spos[i];
    for (int i = t; i < NTRI; i += 256) s2 += star[i];
    #pragma unroll
    for (int off = 32; off; off >>= 1) {
        s1 += __shfl_down(s1, off);
        s2 += __shfl_down(s2, off);
    }
    __shared__ float r1[4], r2[4];
    if (lane == 0) { r1[wave] = s1; r2[wave] = s2; }
    __syncthreads();
    if (t == 0) {
        const float spos_sum = r1[0] + r1[1] + r1[2] + r1[3];
        const float star_sum = r2[0] + r2[1] + r2[2] + r2[3];
        const float star_mean = star_sum / ((float)N * (float)(N - 1)) + EPS;
        out[0] = -spos_sum / (float)N + ALPHA * star_mean;
    }
}

// ---------------------------------------------------------------------------
extern "C" void kernel_launch(void* const* d_in, const int* in_sizes, int n_in,
                              void* d_out, int out_size, void* d_ws, size_t ws_size,
                              hipStream_t stream)
{
    (void)in_sizes; (void)n_in; (void)out_size; (void)ws_size;
    const float* z    = (const float*)d_in[0];
    float*       out  = (float*)d_out;
    u8*          q    = (u8*)d_ws;                                   // 2 MB fp4
    float*       spos = (float*)((char*)d_ws + (size_t)N * DB);      // 4096 f
    float*       star = spos + N;                                    // 528 f

    hipLaunchKernelGGL(norm_spos_kernel, dim3(N),    dim3(256), 0, stream, z, q, spos);
    hipLaunchKernelGGL(gram_kernel,      dim3(NTRI), dim3(512), 0, stream, q, star);
    hipLaunchKernelGGL(finalize_kernel,  dim3(1),    dim3(256), 0, stream, spos, star, out);
}